// Round 1
// baseline (33102.335 us; speedup 1.0000x reference)
//
#include <hip/hip_runtime.h>
#include <math.h>

#define B_SZ 1024
#define N_SZ 100000
#define D_SZ 512
#define TB 32   // queries per block (kernel 2)
#define TN 16   // dataset rows per LDS tile

// ---------------- K1: dataset row norms -> ws ----------------
__global__ __launch_bounds__(256) void norms_kernel(const float* __restrict__ ds,
                                                    float* __restrict__ norms) {
    int wave = threadIdx.x >> 6, lane = threadIdx.x & 63;
    int row = blockIdx.x * 4 + wave;
    if (row >= N_SZ) return;
    const float4* r = (const float4*)(ds + (size_t)row * D_SZ);
    float4 a = r[lane];
    float4 b = r[lane + 64];
    float s = a.x*a.x + a.y*a.y + a.z*a.z + a.w*a.w
            + b.x*b.x + b.y*b.y + b.z*b.z + b.w*b.w;
    #pragma unroll
    for (int off = 1; off < 64; off <<= 1) s += __shfl_xor(s, off, 64);
    if (lane == 0) norms[row] = s;
}

// ---------------- K2: fused flash-attention partials ----------------
// 256 threads: q = tid>>3 (0..31), dg = tid&7 (dim-group of 64 dims).
// Each thread owns x and acc for (query q, dims dg*64..dg*64+63), held in
// registers with a bank-rotation permutation: element cc of the 16-float4
// slice maps to d = dg*64 + ((cc + 2*dg)&15)*4.  The rotation makes the
// wave's concurrent LDS b128 reads at most 2-way bank-aliased (free, m136).
__global__ __launch_bounds__(256) void attn_partial_kernel(
    const float* __restrict__ x_t, const float* __restrict__ t,
    const float* __restrict__ ds, const float* __restrict__ norms,
    float* __restrict__ m_part, float* __restrict__ l_part,
    float* __restrict__ acc_part, int chunk)
{
    __shared__ float4 Y[TN * 128];   // 16 rows x 512 floats = 32 KB
    __shared__ float  nrm[TN];

    int tid = threadIdx.x;
    int q  = tid >> 3;
    int dg = tid & 7;
    int qb = blockIdx.x * TB;
    int s  = blockIdx.y;
    int n0 = s * chunk;
    int n1 = min(N_SZ, n0 + chunk);

    int gq = qb + q;
    float tv = t[gq];
    float a  = tv;
    float bt = 1.0f - tv;
    float inv2b2 = 1.0f / (2.0f * bt * bt);
    float c1  = 2.0f * a * inv2b2;   // logit = c1*dot - c2m*norm (+const dropped)
    float c2m = a * a * inv2b2;

    float4 xr[16];
    float4 acc[16];
    #pragma unroll
    for (int cc = 0; cc < 16; cc++) {
        int cp = (cc + 2*dg) & 15;
        xr[cc] = *(const float4*)(x_t + (size_t)gq * D_SZ + dg*64 + cp*4);
        acc[cc] = make_float4(0.f, 0.f, 0.f, 0.f);
    }
    float m = -1e30f, l = 0.0f;

    for (int nt = n0; nt < n1; nt += TN) {
        int nvalid = min(TN, n1 - nt);
        // stage dataset tile (coalesced float4 global loads)
        #pragma unroll
        for (int k = 0; k < 8; k++) {
            int idx = k*256 + tid;
            int row = idx >> 7, col = idx & 127;
            float4 v = make_float4(0.f, 0.f, 0.f, 0.f);
            if (row < nvalid) v = *(const float4*)(ds + (size_t)(nt+row)*D_SZ + col*4);
            Y[idx] = v;
        }
        if (tid < TN) nrm[tid] = (tid < nvalid) ? norms[nt + tid] : 0.0f;
        __syncthreads();

        // phase A: logits for the tile
        float lg[TN];
        #pragma unroll
        for (int i = 0; i < TN; i++) {
            float dot = 0.f;
            const float4* yr = Y + i*128 + dg*16;
            #pragma unroll
            for (int cc = 0; cc < 16; cc++) {
                int cp = (cc + 2*dg) & 15;
                float4 y = yr[cp];
                dot += xr[cc].x*y.x + xr[cc].y*y.y + xr[cc].z*y.z + xr[cc].w*y.w;
            }
            // butterfly over the 8 dim-group lanes -> all 8 hold the full dot
            dot += __shfl_xor(dot, 1, 64);
            dot += __shfl_xor(dot, 2, 64);
            dot += __shfl_xor(dot, 4, 64);
            lg[i] = (i < nvalid) ? (c1*dot - c2m*nrm[i]) : -1e30f;
        }

        // phase B: online softmax update (rescale once per tile)
        float mt = -1e30f;
        #pragma unroll
        for (int i = 0; i < TN; i++) mt = fmaxf(mt, lg[i]);
        float mn = fmaxf(m, mt);
        float alpha = __expf(m - mn);    // first tile: exp(-1e30) == 0
        l *= alpha;
        #pragma unroll
        for (int cc = 0; cc < 16; cc++) {
            acc[cc].x *= alpha; acc[cc].y *= alpha;
            acc[cc].z *= alpha; acc[cc].w *= alpha;
        }
        #pragma unroll
        for (int i = 0; i < TN; i++) {
            float p = __expf(lg[i] - mn); // invalid rows: exp(-huge) == 0
            l += p;
            const float4* yr = Y + i*128 + dg*16;
            #pragma unroll
            for (int cc = 0; cc < 16; cc++) {
                int cp = (cc + 2*dg) & 15;
                float4 y = yr[cp];
                acc[cc].x += p*y.x; acc[cc].y += p*y.y;
                acc[cc].z += p*y.z; acc[cc].w += p*y.w;
            }
        }
        m = mn;
        __syncthreads();
    }

    size_t slot = (size_t)s * B_SZ + gq;
    if (dg == 0) { m_part[slot] = m; l_part[slot] = l; }
    #pragma unroll
    for (int cc = 0; cc < 16; cc++) {
        int cp = (cc + 2*dg) & 15;
        *(float4*)(acc_part + slot * D_SZ + dg*64 + cp*4) = acc[cc];
    }
}

// ---------------- K3: combine splits + epilogue ----------------
__global__ __launch_bounds__(256) void combine_kernel(
    const float* __restrict__ x_t, const float* __restrict__ t,
    const float* __restrict__ m_part, const float* __restrict__ l_part,
    const float* __restrict__ acc_part, float* __restrict__ out, int nsplit)
{
    int q = blockIdx.x;
    int tid = threadIdx.x;
    float M = -1e30f;
    for (int s = 0; s < nsplit; s++) M = fmaxf(M, m_part[(size_t)s*B_SZ + q]);
    float L = 0.f;
    for (int s = 0; s < nsplit; s++)
        L += l_part[(size_t)s*B_SZ + q] * __expf(m_part[(size_t)s*B_SZ + q] - M);

    float tv = t[q];
    float bt = 1.0f - tv;
    float coeff = 1.0f + tv / bt;       // data_coeff = 1 + a/b
    float invb  = 1.0f / bt;
    float invL  = 1.0f / L;             // L >= 1 always (max row has p = 1)

    int d = tid * 2;
    float2 w = make_float2(0.f, 0.f);
    for (int s = 0; s < nsplit; s++) {
        float sc = __expf(m_part[(size_t)s*B_SZ + q] - M);
        float2 av = *(const float2*)(acc_part + ((size_t)s*B_SZ + q)*D_SZ + d);
        w.x += sc*av.x; w.y += sc*av.y;
    }
    float2 xv = *(const float2*)(x_t + (size_t)q*D_SZ + d);
    float2 o;
    o.x = -invb*xv.x + coeff*w.x*invL;
    o.y = -invb*xv.y + coeff*w.y*invL;
    *(float2*)(out + (size_t)q*D_SZ + d) = o;
}

extern "C" void kernel_launch(void* const* d_in, const int* in_sizes, int n_in,
                              void* d_out, int out_size, void* d_ws, size_t ws_size,
                              hipStream_t stream) {
    const float* x_t = (const float*)d_in[0];
    const float* t   = (const float*)d_in[1];
    const float* ds  = (const float*)d_in[2];
    float* out = (float*)d_out;
    float* ws  = (float*)d_ws;

    const size_t NORM_N = 100352;  // N rounded up to multiple of 256
    // pick nsplit to fit ws: norms + nsplit*B*(D+2) floats
    size_t avail = ws_size / 4;
    int nsplit = 16;
    while (nsplit > 1 &&
           NORM_N + (size_t)nsplit * B_SZ * (D_SZ + 2) > avail) nsplit >>= 1;

    float* norms    = ws;
    float* m_part   = ws + NORM_N;
    float* l_part   = m_part + (size_t)nsplit * B_SZ;
    float* acc_part = l_part + (size_t)nsplit * B_SZ;
    int chunk = (N_SZ + nsplit - 1) / nsplit;

    norms_kernel<<<dim3(N_SZ / 4), dim3(256), 0, stream>>>(ds, norms);
    attn_partial_kernel<<<dim3(B_SZ / TB, nsplit), dim3(256), 0, stream>>>(
        x_t, t, ds, norms, m_part, l_part, acc_part, chunk);
    combine_kernel<<<dim3(B_SZ), dim3(256), 0, stream>>>(
        x_t, t, m_part, l_part, acc_part, out, nsplit);
}

// Round 3
// 4747.320 us; speedup vs baseline: 6.9728x; 6.9728x over previous
//
#include <hip/hip_runtime.h>
#include <math.h>

#define B_SZ 1024
#define N_SZ 100000
#define D_SZ 512
#define TB 32    // queries per block
#define TN 32    // dataset rows per LDS tile
#define QT 4     // queries per thread

// ---------------- K1: dataset row norms -> ws ----------------
__global__ __launch_bounds__(256) void norms_kernel(const float* __restrict__ ds,
                                                    float* __restrict__ norms) {
    int wave = threadIdx.x >> 6, lane = threadIdx.x & 63;
    int row = blockIdx.x * 4 + wave;
    if (row >= N_SZ) return;
    const float4* r = (const float4*)(ds + (size_t)row * D_SZ);
    float4 a = r[lane];
    float4 b = r[lane + 64];
    float s = a.x*a.x + a.y*a.y + a.z*a.z + a.w*a.w
            + b.x*b.x + b.y*b.y + b.z*b.z + b.w*b.w;
    #pragma unroll
    for (int off = 1; off < 64; off <<= 1) s += __shfl_xor(s, off, 64);
    if (lane == 0) norms[row] = s;
}

// DPP rotate-add within rows of 16 lanes (VALU pipe, not DS).
// CTRL must be an integer constant expression -> template parameter.
template <int CTRL>
__device__ __forceinline__ float dpp_ror_add(float v) {
    int x = __builtin_amdgcn_update_dpp(0, __float_as_int(v), CTRL, 0xF, 0xF, false);
    return v + __int_as_float(x);
}
// full reduce across the 32-lane dim group (identical in all 32 lanes)
__device__ __forceinline__ float reduce32(float v) {
    v = dpp_ror_add<0x128>(v);          // row_ror:8
    v = dpp_ror_add<0x124>(v);          // row_ror:4
    v = dpp_ror_add<0x122>(v);          // row_ror:2
    v = dpp_ror_add<0x121>(v);          // row_ror:1  -> sum of 16-lane row
    v += __shfl_xor(v, 16, 64);         // merge the two 16-rows of the half
    return v;
}

// ---------------- K2: fused single-pass flash partials ----------------
// 256 threads: qg = tid>>5 (4 queries each), dimg = tid&31.
// Thread's 16 dims: d = c*128 + dimg*4 + {0..3}, c = 0..3  -> each wave LDS
// read instruction touches 32 CONSECUTIVE float4s (broadcast pairs): minimal
// bank aliasing. Each Y element is read from LDS exactly once per query-group.
__global__ __launch_bounds__(256, 2) void attn_kernel(
    const float* __restrict__ x_t, const float* __restrict__ t,
    const float* __restrict__ ds, const float* __restrict__ norms,
    float* __restrict__ m_part, float* __restrict__ l_part,
    float* __restrict__ acc_part, int chunk)
{
    __shared__ float4 Y[TN * 128];   // 32 rows x 512 floats = 64 KB
    __shared__ float  nrmS[TN];

    int tid  = threadIdx.x;
    int qg   = tid >> 5;
    int dimg = tid & 31;
    int qb   = blockIdx.x * TB;
    int s    = blockIdx.y;
    int n0   = s * chunk;
    int n1   = min(N_SZ, n0 + chunk);

    float  c1[QT], c2m[QT], m[QT], l[QT];
    float4 xr[QT][4], acc[QT][4];
    #pragma unroll
    for (int q = 0; q < QT; q++) {
        int gq = qb + qg * QT + q;
        float tv = t[gq];
        float bt = 1.0f - tv;
        float i2 = 1.0f / (2.0f * bt * bt);
        c1[q]  = 2.0f * tv * i2;
        c2m[q] = tv * tv * i2;
        m[q] = -1e30f; l[q] = 0.0f;
        #pragma unroll
        for (int c = 0; c < 4; c++) {
            xr[q][c] = *(const float4*)(x_t + (size_t)gq * D_SZ + c * 128 + dimg * 4);
            acc[q][c] = make_float4(0.f, 0.f, 0.f, 0.f);
        }
    }

    for (int nt = n0; nt < n1; nt += TN) {
        int nvalid = min(TN, n1 - nt);
        __syncthreads();   // previous tile's reads complete before overwrite
        #pragma unroll
        for (int j = 0; j < 16; j++) {
            int idx = j * 256 + tid;
            int row = idx >> 7, col = idx & 127;
            if (row < nvalid)
                Y[idx] = *(const float4*)(ds + (size_t)(nt + row) * D_SZ + col * 4);
        }
        if (tid < nvalid) nrmS[tid] = norms[nt + tid];
        __syncthreads();

        const float4* yb = Y + dimg;
        #pragma unroll 1
        for (int i = 0; i < nvalid; i++) {
            float4 y0 = yb[i * 128 +  0];
            float4 y1 = yb[i * 128 + 32];
            float4 y2 = yb[i * 128 + 64];
            float4 y3 = yb[i * 128 + 96];
            float nv = nrmS[i];
            float dq[QT];
            #pragma unroll
            for (int q = 0; q < QT; q++) {
                float d0 = xr[q][0].x * y0.x;
                d0 = fmaf(xr[q][0].y, y0.y, d0);
                d0 = fmaf(xr[q][0].z, y0.z, d0);
                d0 = fmaf(xr[q][0].w, y0.w, d0);
                d0 = fmaf(xr[q][1].x, y1.x, d0);
                d0 = fmaf(xr[q][1].y, y1.y, d0);
                d0 = fmaf(xr[q][1].z, y1.z, d0);
                d0 = fmaf(xr[q][1].w, y1.w, d0);
                d0 = fmaf(xr[q][2].x, y2.x, d0);
                d0 = fmaf(xr[q][2].y, y2.y, d0);
                d0 = fmaf(xr[q][2].z, y2.z, d0);
                d0 = fmaf(xr[q][2].w, y2.w, d0);
                d0 = fmaf(xr[q][3].x, y3.x, d0);
                d0 = fmaf(xr[q][3].y, y3.y, d0);
                d0 = fmaf(xr[q][3].z, y3.z, d0);
                d0 = fmaf(xr[q][3].w, y3.w, d0);
                dq[q] = d0;
            }
            #pragma unroll
            for (int q = 0; q < QT; q++) dq[q] = reduce32(dq[q]);

            #pragma unroll
            for (int q = 0; q < QT; q++) {
                float lg = fmaf(c1[q], dq[q], -c2m[q] * nv);
                if (lg > m[q]) {           // rare (~9 of 6250 rows per query)
                    float al = __expf(m[q] - lg);
                    l[q] *= al;
                    #pragma unroll
                    for (int c = 0; c < 4; c++) {
                        acc[q][c].x *= al; acc[q][c].y *= al;
                        acc[q][c].z *= al; acc[q][c].w *= al;
                    }
                    m[q] = lg;
                }
                float p = __expf(lg - m[q]);
                l[q] += p;
                acc[q][0].x = fmaf(p, y0.x, acc[q][0].x);
                acc[q][0].y = fmaf(p, y0.y, acc[q][0].y);
                acc[q][0].z = fmaf(p, y0.z, acc[q][0].z);
                acc[q][0].w = fmaf(p, y0.w, acc[q][0].w);
                acc[q][1].x = fmaf(p, y1.x, acc[q][1].x);
                acc[q][1].y = fmaf(p, y1.y, acc[q][1].y);
                acc[q][1].z = fmaf(p, y1.z, acc[q][1].z);
                acc[q][1].w = fmaf(p, y1.w, acc[q][1].w);
                acc[q][2].x = fmaf(p, y2.x, acc[q][2].x);
                acc[q][2].y = fmaf(p, y2.y, acc[q][2].y);
                acc[q][2].z = fmaf(p, y2.z, acc[q][2].z);
                acc[q][2].w = fmaf(p, y2.w, acc[q][2].w);
                acc[q][3].x = fmaf(p, y3.x, acc[q][3].x);
                acc[q][3].y = fmaf(p, y3.y, acc[q][3].y);
                acc[q][3].z = fmaf(p, y3.z, acc[q][3].z);
                acc[q][3].w = fmaf(p, y3.w, acc[q][3].w);
            }
        }
    }

    size_t base = (size_t)s * B_SZ;
    #pragma unroll
    for (int q = 0; q < QT; q++) {
        int gq = qb + qg * QT + q;
        size_t slot = base + gq;
        if (dimg == 0) { m_part[slot] = m[q]; l_part[slot] = l[q]; }
        #pragma unroll
        for (int c = 0; c < 4; c++)
            *(float4*)(acc_part + slot * D_SZ + c * 128 + dimg * 4) = acc[q][c];
    }
}

// ---------------- K3: combine splits + epilogue ----------------
__global__ __launch_bounds__(256) void combine_kernel(
    const float* __restrict__ x_t, const float* __restrict__ t,
    const float* __restrict__ m_part, const float* __restrict__ l_part,
    const float* __restrict__ acc_part, float* __restrict__ out, int nsplit)
{
    int q = blockIdx.x;
    int tid = threadIdx.x;
    float M = -1e30f;
    for (int s = 0; s < nsplit; s++) M = fmaxf(M, m_part[(size_t)s*B_SZ + q]);
    float L = 0.f;
    for (int s = 0; s < nsplit; s++)
        L += l_part[(size_t)s*B_SZ + q] * __expf(m_part[(size_t)s*B_SZ + q] - M);

    float tv = t[q];
    float bt = 1.0f - tv;
    float coeff = 1.0f + tv / bt;
    float invb  = 1.0f / bt;
    float invL  = 1.0f / L;

    int d = tid * 2;
    float2 w = make_float2(0.f, 0.f);
    for (int s = 0; s < nsplit; s++) {
        float sc = __expf(m_part[(size_t)s*B_SZ + q] - M);
        float2 av = *(const float2*)(acc_part + ((size_t)s*B_SZ + q)*D_SZ + d);
        w.x += sc*av.x; w.y += sc*av.y;
    }
    float2 xv = *(const float2*)(x_t + (size_t)q*D_SZ + d);
    float2 o;
    o.x = -invb*xv.x + coeff*w.x*invL;
    o.y = -invb*xv.y + coeff*w.y*invL;
    *(float2*)(out + (size_t)q*D_SZ + d) = o;
}

extern "C" void kernel_launch(void* const* d_in, const int* in_sizes, int n_in,
                              void* d_out, int out_size, void* d_ws, size_t ws_size,
                              hipStream_t stream) {
    const float* x_t = (const float*)d_in[0];
    const float* t   = (const float*)d_in[1];
    const float* ds  = (const float*)d_in[2];
    float* out = (float*)d_out;
    float* ws  = (float*)d_ws;

    const size_t NORM_N = 100352;
    size_t avail = ws_size / 4;
    int nsplit = 16;
    while (nsplit > 1 &&
           NORM_N + (size_t)nsplit * B_SZ * (D_SZ + 2) > avail) nsplit >>= 1;

    float* norms    = ws;
    float* m_part   = ws + NORM_N;
    float* l_part   = m_part + (size_t)nsplit * B_SZ;
    float* acc_part = l_part + (size_t)nsplit * B_SZ;
    int chunk = (N_SZ + nsplit - 1) / nsplit;

    norms_kernel<<<dim3(N_SZ / 4), dim3(256), 0, stream>>>(ds, norms);
    attn_kernel<<<dim3(B_SZ / TB, nsplit), dim3(256), 0, stream>>>(
        x_t, t, ds, norms, m_part, l_part, acc_part, chunk);
    combine_kernel<<<dim3(B_SZ), dim3(256), 0, stream>>>(
        x_t, t, m_part, l_part, acc_part, out, nsplit);
}

// Round 5
// 1282.490 us; speedup vs baseline: 25.8110x; 3.7016x over previous
//
#include <hip/hip_runtime.h>
#include <math.h>

#define B_SZ 1024
#define N_SZ 100000
#define D_SZ 512
#define NBLK 3125   // N/32 row-tiles (exact: 100000 = 3125*32)

typedef __attribute__((ext_vector_type(8))) short short8;
typedef __attribute__((ext_vector_type(16))) float float16;

__device__ __forceinline__ unsigned f2bf(float x) {
    unsigned u = __float_as_uint(x);
    u += 0x7FFFu + ((u >> 16) & 1u);
    return u >> 16;                       // RNE bf16 bits in low 16
}
__device__ __forceinline__ float bf2f(unsigned h) {
    return __uint_as_float(h << 16);
}

// ---------------- PRE: split dataset to Yh/Yl, transposed Yt, norms; split X ----
__global__ __launch_bounds__(256) void pre_kernel(
    const float* __restrict__ ds, const float* __restrict__ x_t,
    short* __restrict__ Yh, short* __restrict__ Yl, short* __restrict__ Yt,
    short* __restrict__ Xh, short* __restrict__ Xl, float* __restrict__ norms)
{
    __shared__ unsigned short YS[32 * 512];   // hi tile, [n][d]
    const int bx = blockIdx.x, tid = threadIdx.x;
    if (bx < NBLK) {
        const int row = tid >> 3, seg = tid & 7;
        const size_t g = (size_t)(bx * 32 + row) * 512 + seg * 64;
        const int ls = row * 512 + seg * 64;
        float nrm = 0.f;
        #pragma unroll
        for (int i = 0; i < 16; i++) {
            float4 v = *(const float4*)(ds + g + i * 4);
            nrm += v.x*v.x + v.y*v.y + v.z*v.z + v.w*v.w;
            unsigned h0 = f2bf(v.x), h1 = f2bf(v.y), h2 = f2bf(v.z), h3 = f2bf(v.w);
            unsigned l0 = f2bf(v.x - bf2f(h0)), l1 = f2bf(v.y - bf2f(h1));
            unsigned l2 = f2bf(v.z - bf2f(h2)), l3 = f2bf(v.w - bf2f(h3));
            uint2 hw = make_uint2(h0 | (h1 << 16), h2 | (h3 << 16));
            uint2 lw = make_uint2(l0 | (l1 << 16), l2 | (l3 << 16));
            *(uint2*)(Yh + g + i * 4) = hw;
            *(uint2*)(Yl + g + i * 4) = lw;
            *(uint2*)(YS + ls + i * 4) = hw;
        }
        nrm += __shfl_xor(nrm, 1, 64);
        nrm += __shfl_xor(nrm, 2, 64);
        nrm += __shfl_xor(nrm, 4, 64);
        if ((tid & 7) == 0) norms[bx * 32 + row] = nrm;
        __syncthreads();
        // write transposed block Yt[bx][d][n']  (rows of 32 bf16 = 64 B)
        #pragma unroll
        for (int r = 0; r < 2; r++) {
            const int d = tid + r * 256;
            unsigned w[16];
            #pragma unroll
            for (int j = 0; j < 16; j++) {
                unsigned lo = YS[(2 * j) * 512 + d];
                unsigned hi = YS[(2 * j + 1) * 512 + d];
                w[j] = lo | (hi << 16);
            }
            uint4* dst = (uint4*)(Yt + (size_t)bx * 16384 + d * 32);
            dst[0] = make_uint4(w[0], w[1], w[2], w[3]);
            dst[1] = make_uint4(w[4], w[5], w[6], w[7]);
            dst[2] = make_uint4(w[8], w[9], w[10], w[11]);
            dst[3] = make_uint4(w[12], w[13], w[14], w[15]);
        }
    } else {
        const int xb = bx - NBLK;   // 0..31, X split: 1024x512 f32
        #pragma unroll
        for (int k = 0; k < 16; k++) {
            const size_t i4 = (size_t)xb * 4096 + k * 256 + tid;
            float4 v = *(const float4*)(x_t + i4 * 4);
            unsigned h0 = f2bf(v.x), h1 = f2bf(v.y), h2 = f2bf(v.z), h3 = f2bf(v.w);
            unsigned l0 = f2bf(v.x - bf2f(h0)), l1 = f2bf(v.y - bf2f(h1));
            unsigned l2 = f2bf(v.z - bf2f(h2)), l3 = f2bf(v.w - bf2f(h3));
            *(uint2*)(Xh + i4 * 4) = make_uint2(h0 | (h1 << 16), h2 | (h3 << 16));
            *(uint2*)(Xl + i4 * 4) = make_uint2(l0 | (l1 << 16), l2 | (l3 << 16));
        }
    }
}

// ---------------- MAIN: producer/consumer MFMA flash ----------------
// 512 thr = 8 waves. waves 0-3: S^T = Y.X^T (k-split 128 dims each, 3 bf16
// passes), LDS-reduce, softmax -> P-buf. waves 4-7: O^T += Yt^T.P^T for a
// 128-dim slice, pipelined one tile behind. Q-tile 64, row-tile 32.
__global__ __launch_bounds__(512, 2) void attn_kernel(
    const float* __restrict__ t,
    const short* __restrict__ Xh, const short* __restrict__ Xl,
    const short* __restrict__ Yh, const short* __restrict__ Yl,
    const short* __restrict__ Yt, const float* __restrict__ norms,
    float* __restrict__ m_part, float* __restrict__ l_part,
    float* __restrict__ acc_part, int chunk)
{
    __shared__ short YhL[32 * 512];          // 32 KB
    __shared__ short YlL[32 * 512];          // 32 KB
    __shared__ float slots[4 * 64 * 33];     // S partials, pitch 33 (bank-safe b32)
    __shared__ float Pbuf[64 * 36];          // P (exp'ed), pitch 36 (16B-aligned rows)
    __shared__ float c1A[64], c2A[64], mAs[64], lAs[64], alA[64];
    __shared__ float nrmL[32];

    const int tid = threadIdx.x;
    const int wave = tid >> 6, lane = tid & 63;
    const int half = lane >> 5, l31 = lane & 31;
    const int qb = blockIdx.x * 64;
    const int s = blockIdx.y;
    const int n0s = s * chunk;
    const int n1 = min(N_SZ, n0s + chunk);
    const int numTiles = (n1 - n0s + 31) >> 5;

    if (tid < 64) {
        float tv = t[qb + tid];
        float bt = 1.0f - tv;
        float i2 = 1.0f / (2.0f * bt * bt);
        c1A[tid] = 2.0f * tv * i2;
        c2A[tid] = tv * tv * i2;
        mAs[tid] = -1e30f;
        lAs[tid] = 0.0f;
        alA[tid] = 0.0f;
    }
    __syncthreads();

    if (wave < 4) {
        // ================= PRODUCER =================
        short8 XF[2][8][2];   // [qtile][kchunk][h/l] B-frags, persistent
        #pragma unroll
        for (int qt = 0; qt < 2; qt++)
            #pragma unroll
            for (int kc = 0; kc < 8; kc++) {
                size_t off = (size_t)(qb + qt * 32 + l31) * 512 + wave * 128 + kc * 16 + half * 8;
                XF[qt][kc][0] = *(const short8*)(Xh + off);
                XF[qt][kc][1] = *(const short8*)(Xl + off);
            }

        for (int it = 0; it <= numTiles; ++it) {
            if (it < numTiles) {   // stage tile it
                int n0 = n0s + it * 32;
                #pragma unroll
                for (int j = 0; j < 8; j++) {
                    int r = wave * 8 + j;
                    int gr = n0 + r;
                    if (gr < n1) {
                        const short* gh = Yh + (size_t)gr * 512 + lane * 8;
                        const short* gl = Yl + (size_t)gr * 512 + lane * 8;
                        __builtin_amdgcn_global_load_lds(
                            (const __attribute__((address_space(1))) unsigned int*)gh,
                            (__attribute__((address_space(3))) unsigned int*)&YhL[r * 512], 16, 0, 0);
                        __builtin_amdgcn_global_load_lds(
                            (const __attribute__((address_space(1))) unsigned int*)gl,
                            (__attribute__((address_space(3))) unsigned int*)&YlL[r * 512], 16, 0, 0);
                    } else {
                        short8 z;
                        #pragma unroll
                        for (int e = 0; e < 8; e++) z[e] = 0;
                        *(short8*)(&YhL[r * 512 + lane * 8]) = z;
                        *(short8*)(&YlL[r * 512 + lane * 8]) = z;
                    }
                }
                if (wave == 0 && lane < 32)
                    nrmL[lane] = (n0 + lane < n1) ? norms[n0 + lane] : 1e30f;
            }
            __syncthreads();   // (a) tile staged

            if (it < numTiles) {
                float16 S0, S1;
                #pragma unroll
                for (int e = 0; e < 16; e++) { S0[e] = 0.f; S1[e] = 0.f; }
                #pragma unroll
                for (int kc = 0; kc < 8; kc++) {
                    const int koff = wave * 128 + kc * 16 + half * 8;
                    short8 Ah = *(const short8*)(YhL + l31 * 512 + koff);
                    short8 Al = *(const short8*)(YlL + l31 * 512 + koff);
                    S0 = __builtin_amdgcn_mfma_f32_32x32x16_bf16(Ah, XF[0][kc][0], S0, 0, 0, 0);
                    S0 = __builtin_amdgcn_mfma_f32_32x32x16_bf16(Ah, XF[0][kc][1], S0, 0, 0, 0);
                    S0 = __builtin_amdgcn_mfma_f32_32x32x16_bf16(Al, XF[0][kc][0], S0, 0, 0, 0);
                    S1 = __builtin_amdgcn_mfma_f32_32x32x16_bf16(Ah, XF[1][kc][0], S1, 0, 0, 0);
                    S1 = __builtin_amdgcn_mfma_f32_32x32x16_bf16(Ah, XF[1][kc][1], S1, 0, 0, 0);
                    S1 = __builtin_amdgcn_mfma_f32_32x32x16_bf16(Al, XF[1][kc][0], S1, 0, 0, 0);
                }
                float* sb = &slots[wave * 2112];
                #pragma unroll
                for (int qt = 0; qt < 2; qt++) {
                    float* rowp = sb + (qt * 32 + l31) * 33;
                    #pragma unroll
                    for (int r = 0; r < 16; r++) {
                        int n = (r & 3) + 8 * (r >> 2) + 4 * half;
                        rowp[n] = qt ? S1[r] : S0[r];
                    }
                }
            }
            __syncthreads();   // (b) partials ready

            if (it < numTiles) {   // reduce + softmax -> Pbuf
                int ql = lane >> 2, nq = lane & 3;
                int q = wave * 16 + ql;
                float c1q = c1A[q], c2q = c2A[q];
                float lg[8];
                float mt = -1e30f;
                #pragma unroll
                for (int j = 0; j < 8; j++) {
                    int n = nq * 8 + j;
                    float dd = slots[q * 33 + n] + slots[2112 + q * 33 + n]
                             + slots[4224 + q * 33 + n] + slots[6336 + q * 33 + n];
                    lg[j] = c1q * dd - c2q * nrmL[n];
                    mt = fmaxf(mt, lg[j]);
                }
                mt = fmaxf(mt, __shfl_xor(mt, 1, 64));
                mt = fmaxf(mt, __shfl_xor(mt, 2, 64));
                float mo = mAs[q];
                float mn = fmaxf(mo, mt);
                float al = __expf(mo - mn);
                float ls = 0.f;
                #pragma unroll
                for (int j = 0; j < 8; j++) {
                    float p = __expf(lg[j] - mn);
                    Pbuf[q * 36 + nq * 8 + j] = p;
                    ls += p;
                }
                ls += __shfl_xor(ls, 1, 64);
                ls += __shfl_xor(ls, 2, 64);
                if (nq == 0) {
                    mAs[q] = mn;
                    lAs[q] = lAs[q] * al + ls;
                    alA[q] = al;
                }
            }
            __syncthreads();   // (c) Pbuf/alphas ready
        }
        if (tid < 64) {
            m_part[(size_t)s * B_SZ + qb + tid] = mAs[tid];
            l_part[(size_t)s * B_SZ + qb + tid] = lAs[tid];
        }
    } else {
        // ================= CONSUMER =================
        const int dbase = (wave - 4) * 128;
        float16 O[4][2];
        #pragma unroll
        for (int dt = 0; dt < 4; dt++)
            #pragma unroll
            for (int qt = 0; qt < 2; qt++)
                #pragma unroll
                for (int e = 0; e < 16; e++) O[dt][qt][e] = 0.f;

        for (int it = 0; it <= numTiles; ++it) {
            __syncthreads();   // (a)
            if (it > 0) {      // PV(it-1)
                int blk = (n0s + (it - 1) * 32) >> 5;
                const short* yb = Yt + (size_t)blk * 16384;
                float al0 = alA[l31], al1 = alA[32 + l31];
                #pragma unroll
                for (int dt = 0; dt < 4; dt++) {
                    O[dt][0] *= al0;
                    O[dt][1] *= al1;
                }
                short8 AF[4][2];
                #pragma unroll
                for (int dt = 0; dt < 4; dt++)
                    #pragma unroll
                    for (int kc = 0; kc < 2; kc++)
                        AF[dt][kc] = *(const short8*)(yb + (dbase + dt * 32 + l31) * 32 + kc * 16 + half * 8);
                short8 BF[2][2];
                #pragma unroll
                for (int qt = 0; qt < 2; qt++)
                    #pragma unroll
                    for (int kc = 0; kc < 2; kc++) {
                        const float* pr = &Pbuf[(qt * 32 + l31) * 36 + kc * 16 + half * 8];
                        float4 pa = *(const float4*)pr;
                        float4 pb = *(const float4*)(pr + 4);
                        short8 b;
                        b[0] = (short)f2bf(pa.x); b[1] = (short)f2bf(pa.y);
                        b[2] = (short)f2bf(pa.z); b[3] = (short)f2bf(pa.w);
                        b[4] = (short)f2bf(pb.x); b[5] = (short)f2bf(pb.y);
                        b[6] = (short)f2bf(pb.z); b[7] = (short)f2bf(pb.w);
                        BF[qt][kc] = b;
                    }
                #pragma unroll
                for (int dt = 0; dt < 4; dt++)
                    #pragma unroll
                    for (int qt = 0; qt < 2; qt++)
                        #pragma unroll
                        for (int kc = 0; kc < 2; kc++)
                            O[dt][qt] = __builtin_amdgcn_mfma_f32_32x32x16_bf16(
                                AF[dt][kc], BF[qt][kc], O[dt][qt], 0, 0, 0);
            }
            __syncthreads();   // (b)
            __syncthreads();   // (c)
        }
        // write O^T partials -> acc_part[s][q][d]
        #pragma unroll
        for (int dt = 0; dt < 4; dt++)
            #pragma unroll
            for (int qt = 0; qt < 2; qt++) {
                int q = qb + qt * 32 + l31;
                float* op = acc_part + ((size_t)s * B_SZ + q) * D_SZ + dbase + dt * 32 + 4 * half;
                #pragma unroll
                for (int rg = 0; rg < 4; rg++) {
                    float4 v = make_float4(O[dt][qt][4 * rg], O[dt][qt][4 * rg + 1],
                                           O[dt][qt][4 * rg + 2], O[dt][qt][4 * rg + 3]);
                    *(float4*)(op + 8 * rg) = v;
                }
            }
    }
}

// ---------------- COMBINE: merge splits + epilogue ----------------
__global__ __launch_bounds__(256) void combine_kernel(
    const float* __restrict__ x_t, const float* __restrict__ t,
    const float* __restrict__ m_part, const float* __restrict__ l_part,
    const float* __restrict__ acc_part, float* __restrict__ out, int nsplit)
{
    int q = blockIdx.x;
    int tid = threadIdx.x;
    float M = -1e30f;
    for (int s = 0; s < nsplit; s++) M = fmaxf(M, m_part[(size_t)s * B_SZ + q]);
    float L = 0.f;
    for (int s = 0; s < nsplit; s++)
        L += l_part[(size_t)s * B_SZ + q] * __expf(m_part[(size_t)s * B_SZ + q] - M);

    float tv = t[q];
    float bt = 1.0f - tv;
    float coeff = 1.0f + tv / bt;
    float invb = 1.0f / bt;
    float invL = 1.0f / L;

    int d = tid * 2;
    float2 w = make_float2(0.f, 0.f);
    for (int s = 0; s < nsplit; s++) {
        float sc = __expf(m_part[(size_t)s * B_SZ + q] - M);
        float2 av = *(const float2*)(acc_part + ((size_t)s * B_SZ + q) * D_SZ + d);
        w.x += sc * av.x; w.y += sc * av.y;
    }
    float2 xv = *(const float2*)(x_t + (size_t)q * D_SZ + d);
    float2 o;
    o.x = -invb * xv.x + coeff * w.x * invL;
    o.y = -invb * xv.y + coeff * w.y * invL;
    *(float2*)(out + (size_t)q * D_SZ + d) = o;
}

extern "C" void kernel_launch(void* const* d_in, const int* in_sizes, int n_in,
                              void* d_out, int out_size, void* d_ws, size_t ws_size,
                              hipStream_t stream) {
    const float* x_t = (const float*)d_in[0];
    const float* t   = (const float*)d_in[1];
    const float* ds  = (const float*)d_in[2];
    float* out = (float*)d_out;

    short* wsS = (short*)d_ws;
    short* Yh = wsS;                              // 51,200,000 shorts
    short* Yl = wsS + 51200000;
    short* Yt = wsS + 102400000;
    short* Xh = wsS + 153600000;                  // 524,288 shorts
    short* Xl = wsS + 154124288;
    float* fbase = (float*)((char*)d_ws + 309297152);   // 16B-aligned
    float* norms = fbase;                         // 100,000 f32 (400,000 B)
    int nsplit = 16;
    while (nsplit > 1 &&
           309697152ULL + (size_t)nsplit * 1024 * 4 * (2 + 512) > ws_size)
        nsplit >>= 1;
    float* m_part = fbase + 100000;
    float* l_part = m_part + (size_t)nsplit * B_SZ;
    float* acc    = l_part + (size_t)nsplit * B_SZ;
    int chunk = 32 * ((N_SZ + 32 * nsplit - 1) / (32 * nsplit));

    pre_kernel<<<dim3(NBLK + 32), dim3(256), 0, stream>>>(ds, x_t, Yh, Yl, Yt, Xh, Xl, norms);
    attn_kernel<<<dim3(16, nsplit), dim3(512), 0, stream>>>(
        t, Xh, Xl, Yh, Yl, Yt, norms, m_part, l_part, acc, chunk);
    combine_kernel<<<dim3(B_SZ), dim3(256), 0, stream>>>(
        x_t, t, m_part, l_part, acc, out, nsplit);
}